// Round 11
// baseline (267.437 us; speedup 1.0000x reference)
//
#include <hip/hip_runtime.h>

#define NN 50000
#define EE 400000
#define CIN 16
#define COUT 32
#define NPB  66                    // nodes per dst-bucket
#define NBKT 758                   // ceil(50000/66)
#define MAXB 1024                  // max edges per bucket (mean 528, sd ~23)
#define NW   (125 * CIN * COUT)    // 64000 weight elems

typedef float f32x4  __attribute__((ext_vector_type(4)));
typedef float f32x16 __attribute__((ext_vector_type(16)));
typedef short short8 __attribute__((ext_vector_type(8)));
typedef int   i32x4  __attribute__((ext_vector_type(4)));
typedef unsigned int u32x4 __attribute__((ext_vector_type(4)));

// ---- workspace layout (bytes) ----
#define W_HIST  0                              // int hist[NBKT]
#define W_CURS  (W_HIST + NBKT*4)              // int cursors[NBKT]
#define W_DEG   (W_CURS + NBKT*4)              // int degi[NN]
#define W_SUM   (W_DEG + NN*4)                 // float gsum[32]
#define W_SUMSQ (W_SUM + 128)                  // float gsumsq[32]
#define W_ZERO  (W_SUMSQ + 128)                // memset range [0, W_ZERO)
#define W_OFFS  W_ZERO                         // int offsets[NBKT+1]
#define W_SORT  ((W_OFFS + (NBKT+1)*4 + 63) & ~63)  // int sorted[EE]
#define W_WBF   (W_SORT + EE*4)                // bf16 wbf[125][2][32][8] = 125 KB

// K1: dst-bucket histogram + in-degree (blocks 0..255) and weight->bf16
// fragment conversion (blocks 256..505). No attr reads needed here.
__global__ __launch_bounds__(256) void k_hist_wconv(
    const int* __restrict__ edst, int* __restrict__ hist, int* __restrict__ degi,
    const float* __restrict__ w, unsigned short* __restrict__ wbf) {
  int b = blockIdx.x;
  if (b < 256) {
    for (int e = b * 256 + threadIdx.x; e < EE; e += 65536) {
      int d = edst[e];
      atomicAdd(&hist[d / NPB], 1);
      atomicAdd(&degi[d], 1);
    }
  } else {
    // pos = ((wi*2+half)*32 + o)*8 + j  <- reads weight[wi][half*8+j][o]
    int pos = (b - 256) * 256 + threadIdx.x;
    if (pos < NW) {
      int j = pos & 7, o = (pos >> 3) & 31, wh = pos >> 8;
      int wi = wh >> 1, half = wh & 1, k = half * 8 + j;
      wbf[pos] = __builtin_bit_cast(unsigned short, (__bf16)w[wi * (CIN*COUT) + k * COUT + o]);
    }
  }
}

// K2: prefix scan over 758 buckets (single block)
__global__ __launch_bounds__(1024) void k_scan(const int* __restrict__ hist,
                                               int* __restrict__ offsets) {
  __shared__ int part[1024];
  int t = threadIdx.x;
  int own = (t < NBKT) ? hist[t] : 0;
  part[t] = own;
  __syncthreads();
  for (int d = 1; d < 1024; d <<= 1) {
    int v = (t >= d) ? part[t - d] : 0;
    __syncthreads();
    part[t] += v;
    __syncthreads();
  }
  if (t < NBKT) offsets[t] = part[t] - own;
  if (t == NBKT - 1) offsets[NBKT] = part[t];
}

// K3: scatter edges into dst-buckets (two-level LDS, 758 cursors)
__global__ __launch_bounds__(256) void k_scatter(
    const int* __restrict__ edst, const int* __restrict__ offsets,
    int* __restrict__ cursors, int* __restrict__ sorted) {
  __shared__ int lcnt[NBKT], lbase[NBKT], lcur[NBKT];
  int tid = threadIdx.x;
  for (int i = tid; i < NBKT; i += 256) { lcnt[i] = 0; lcur[i] = 0; }
  __syncthreads();
  int per = (EE + gridDim.x - 1) / gridDim.x;
  int b0 = blockIdx.x * per, b1 = min(b0 + per, EE);
  for (int e = b0 + tid; e < b1; e += 256) atomicAdd(&lcnt[edst[e] / NPB], 1);
  __syncthreads();
  for (int i = tid; i < NBKT; i += 256)
    if (lcnt[i]) lbase[i] = offsets[i] + atomicAdd(&cursors[i], lcnt[i]);
  __syncthreads();
  for (int e = b0 + tid; e < b1; e += 256) {
    int c = edst[e] / NPB;
    sorted[lbase[c] + atomicAdd(&lcur[c], 1)] = e;
  }
}

// K4: mega kernel. 1024 threads (16 waves), 1 block/CU (150 KB LDS).
// Phase 0: stage all 125 weight fragments into LDS; in-block cell counting
// sort of the bucket's edges. Phase 1: swapped-operand MFMA tiles with
// ballot/ffs multipass; ev operands built ONCE per tile, per-pass AND-mask;
// weight fragments read from LDS (no vmcnt serialization). Merge via LDS
// atomics (+ldst rotation, proven). Phase 2: node math + BN partials.
__global__ __launch_bounds__(1024, 1) void k_mega(
    const float* __restrict__ x, const int* __restrict__ esrc, const int* __restrict__ edst,
    const float* __restrict__ attr, const unsigned short* __restrict__ wbf,
    const int* __restrict__ sorted, const int* __restrict__ offsets,
    const int* __restrict__ degi, const float* __restrict__ root,
    const float* __restrict__ bias, float* __restrict__ out,
    float* __restrict__ gsum, float* __restrict__ gsumsq) {
  __shared__ unsigned short wlds[NW];            // 128000 B
  __shared__ float lagg[NPB * 32];               // 8448 B
  __shared__ int lsorted[MAXB];                  // 4096 B
  __shared__ int lid[MAXB];                      // 4096 B
  __shared__ unsigned char lcellb[MAXB];         // 1024 B
  __shared__ int lcnt[64], lbase[64], lcur[64];  // 768 B
  __shared__ float sred[2][16][32];              // 4096 B
  int bkt = blockIdx.x, tid = threadIdx.x;

  // stage weights: 8000 x 16B, 8 rounds
  for (int i = tid; i < NW / 8; i += 1024)
    *(u32x4*)(wlds + (size_t)i * 8) = *(const u32x4*)(wbf + (size_t)i * 8);
  for (int i = tid; i < NPB * 32; i += 1024) lagg[i] = 0.0f;
  if (tid < 64) { lcnt[tid] = 0; lcur[tid] = 0; }
  __syncthreads();

  int s = offsets[bkt], t = offsets[bkt + 1];
  int cnt = min(t - s, MAXB);

  // in-block cell counting sort (<=1024 edges, 1024 threads: 1 round each)
  if (tid < cnt) {
    int e = sorted[s + tid];
    float v0 = attr[e*3+0]*4.f, v1 = attr[e*3+1]*4.f, v2 = attr[e*3+2]*4.f;
    int l0 = min(max((int)v0,0),3), l1 = min(max((int)v1,0),3), l2 = min(max((int)v2,0),3);
    int c = l0 | (l1 << 2) | (l2 << 4);
    lid[tid] = e; lcellb[tid] = (unsigned char)c;
    atomicAdd(&lcnt[c], 1);
  }
  __syncthreads();
  if (tid == 0) { int r = 0; for (int c = 0; c < 64; ++c) { lbase[c] = r; r += lcnt[c]; } }
  __syncthreads();
  if (tid < cnt) {
    int c = lcellb[tid];
    lsorted[lbase[c] + atomicAdd(&lcur[c], 1)] = lid[tid];
  }
  __syncthreads();

  int lane = tid & 63, col = lane & 31, half = lane >> 5, wv = tid >> 6;
  int nt = (cnt + 31) >> 5;
  for (int ti = wv; ti < nt; ti += 16) {
    int idx = ti * 32 + col;
    bool valid = idx < cnt;
    int e = lsorted[valid ? idx : (cnt - 1)];
    float a0 = attr[e*3+0], a1 = attr[e*3+1], a2 = attr[e*3+2];
    int src = esrc[e], dst = edst[e];
    float v0 = a0*4.f, v1 = a1*4.f, v2 = a2*4.f;
    int l0 = min(max((int)v0,0),3), l1 = min(max((int)v1,0),3), l2 = min(max((int)v2,0),3);
    float f0 = v0-(float)l0, f1 = v1-(float)l1, f2 = v2-(float)l2;
    int mycell = l0 | (l1 << 2) | (l2 << 4);
    float g0 = 1.f-f0, g1 = 1.f-f1, g2 = 1.f-f2;

    const float* xp = x + src * CIN + half * 8;
    float xs[8];
    {
      f32x4 xa = *(const f32x4*)xp, xb = *(const f32x4*)(xp + 4);
#pragma unroll
      for (int j = 0; j < 4; ++j) { xs[j] = xa[j]; xs[j + 4] = xb[j]; }
    }

    // ev operands once per tile: 8 cb x 4 dwords (bf16 pairs of w_cb*xs)
    i32x4 evi[8];
#pragma unroll
    for (int cb = 0; cb < 8; ++cb) {
      float w = ((cb & 1) ? f0 : g0) * (((cb >> 1) & 1) ? f1 : g1)
              * (((cb >> 2) & 1) ? f2 : g2);
      i32x4 v;
#pragma unroll
      for (int m = 0; m < 4; ++m) {
        unsigned lo = (unsigned)__builtin_bit_cast(unsigned short, (__bf16)(w * xs[2*m]));
        unsigned hi = (unsigned)__builtin_bit_cast(unsigned short, (__bf16)(w * xs[2*m+1]));
        v[m] = (int)((hi << 16) | lo);
      }
      evi[cb] = v;
    }

    f32x16 acc;
#pragma unroll
    for (int r = 0; r < 16; ++r) acc[r] = 0.0f;

    unsigned rem = (unsigned)(__ballot(valid) & 0xffffffffull);
    while (rem) {
      int slot = __ffs(rem) - 1;
      int cs = __builtin_amdgcn_readfirstlane(__shfl(mycell, slot, 64));
      unsigned long long bal = __ballot(valid && (mycell == cs));
      int msk = -(int)((bal >> lane) & 1ull);   // act ? -1 : 0
      int c0 = cs & 3, c1 = (cs >> 2) & 3, c2 = cs >> 4;
#pragma unroll
      for (int cb = 0; cb < 8; ++cb) {
        int wi = (c0 + (cb & 1)) + 5 * (c1 + ((cb >> 1) & 1)) + 25 * (c2 + (cb >> 2));
        short8 wvv = *(const short8*)(wlds + (size_t)(((wi * 2 + half) * 32 + col) * 8));
        i32x4 em = evi[cb];
        em[0] &= msk; em[1] &= msk; em[2] &= msk; em[3] &= msk;
        acc = __builtin_amdgcn_mfma_f32_32x32x16_bf16(
            wvv, __builtin_bit_cast(short8, em), acc, 0, 0, 0);
      }
      rem &= ~(unsigned)(bal & 0xffffffffull);
    }

    if (valid) {
      int ldst = dst - bkt * NPB;
#pragma unroll
      for (int r = 0; r < 16; ++r) {
        int o = (r & 3) + 8 * (r >> 2) + 4 * half;
        atomicAdd(&lagg[ldst * 32 + ((o + ldst) & 31)], acc[r]);
      }
    }
  }
  __syncthreads();

  // node phase from LDS
  float s1 = 0.0f, s2 = 0.0f;
  int o = tid & 31;
  for (int nl = tid >> 5; nl < NPB; nl += 32) {
    int n = bkt * NPB + nl;
    if (n < NN) {
      float a = lagg[nl * 32 + ((o + nl) & 31)] / fmaxf((float)degi[n], 1.0f);
      const float* xp = x + n * CIN;
      float r = 0.0f;
#pragma unroll
      for (int i = 0; i < CIN; ++i) r = fmaf(xp[i], root[i * COUT + o], r);
      float hv = a + r + bias[o];
      hv = hv > 0.0f ? hv : expm1f(hv);
      out[n * COUT + o] = hv;
      s1 += hv; s2 += hv * hv;
    }
  }
  s1 += __shfl_xor(s1, 32);
  s2 += __shfl_xor(s2, 32);
  int w = tid >> 6;
  if ((tid & 63) < 32) { sred[0][w][o] = s1; sred[1][w][o] = s2; }
  __syncthreads();
  if (tid < 32) {
    float t1 = 0.0f, t2 = 0.0f;
#pragma unroll
    for (int w2 = 0; w2 < 16; ++w2) { t1 += sred[0][w2][o]; t2 += sred[1][w2][o]; }
    atomicAdd(&gsum[o], t1);
    atomicAdd(&gsumsq[o], t2);
  }
}

// K5: finalize BatchNorm in-place
__global__ void k_bn(float* __restrict__ out, const float* __restrict__ gsum,
                     const float* __restrict__ gsumsq, const float* __restrict__ gamma,
                     const float* __restrict__ beta) {
  int idx = blockIdx.x * blockDim.x + threadIdx.x;
  if (idx >= NN * COUT) return;
  int o = idx & 31;
  float m = gsum[o] * (1.0f / NN);
  float var = gsumsq[o] * (1.0f / NN) - m * m;
  float inv = rsqrtf(var + 1e-5f);
  out[idx] = (out[idx] - m) * inv * gamma[o] + beta[o];
}

extern "C" void kernel_launch(void* const* d_in, const int* in_sizes, int n_in,
                              void* d_out, int out_size, void* d_ws, size_t ws_size,
                              hipStream_t stream) {
  const float* x      = (const float*)d_in[0];
  const int*   ei     = (const int*)d_in[1];
  const float* attr   = (const float*)d_in[2];
  const float* weight = (const float*)d_in[3];
  const float* root   = (const float*)d_in[4];
  const float* bias   = (const float*)d_in[5];
  const float* gamma  = (const float*)d_in[6];
  const float* beta   = (const float*)d_in[7];
  float* out = (float*)d_out;
  char* ws = (char*)d_ws;
  const int* esrc = ei;
  const int* edst = ei + EE;

  int*   hist    = (int*)(ws + W_HIST);
  int*   cursors = (int*)(ws + W_CURS);
  int*   degi    = (int*)(ws + W_DEG);
  float* gsum    = (float*)(ws + W_SUM);
  float* gsumsq  = (float*)(ws + W_SUMSQ);
  int*   offsets = (int*)(ws + W_OFFS);
  int*   sorted  = (int*)(ws + W_SORT);
  unsigned short* wbf = (unsigned short*)(ws + W_WBF);

  hipMemsetAsync(ws, 0, W_ZERO, stream);
  k_hist_wconv<<<506, 256, 0, stream>>>(edst, hist, degi, weight, wbf);
  k_scan<<<1, 1024, 0, stream>>>(hist, offsets);
  k_scatter<<<512, 256, 0, stream>>>(edst, offsets, cursors, sorted);
  k_mega<<<NBKT, 1024, 0, stream>>>(x, esrc, edst, attr, wbf, sorted, offsets,
                                    degi, root, bias, out, gsum, gsumsq);
  k_bn<<<(NN * COUT) / 256, 256, 0, stream>>>(out, gsum, gsumsq, gamma, beta);
}

// Round 12
// 115.020 us; speedup vs baseline: 2.3251x; 2.3251x over previous
//
#include <hip/hip_runtime.h>

#define NN 50000
#define EE 400000
#define CIN 16
#define COUT 32
#define NTILES (EE / 32)

typedef float f32x4  __attribute__((ext_vector_type(4)));
typedef float f32x16 __attribute__((ext_vector_type(16)));
typedef short short8 __attribute__((ext_vector_type(8)));

// ---- workspace layout (bytes) ----
#define W_AGG   0                      // float agg[NN*COUT] = 6.4 MB (zeroed in k_hist)
#define W_DEG   (NN*COUT*4)            // int degi[NN]
#define W_HIST  (W_DEG + NN*4)         // int hist[64]
#define W_CUR   (W_HIST + 256)         // int cursors[64]
#define W_SUM   (W_CUR + 256)          // float gsum[32]
#define W_SUMSQ (W_SUM + 128)          // float gsumsq[32]
#define W_ZEND  (W_SUMSQ + 128)        // memset [W_DEG, W_ZEND)
#define W_SORT  W_ZEND                 // int sorted[EE]

__device__ __forceinline__ void cell_of(float a0, float a1, float a2,
                                        int& l0, int& l1, int& l2,
                                        float& f0, float& f1, float& f2) {
  float v0 = a0 * 4.0f, v1 = a1 * 4.0f, v2 = a2 * 4.0f;
  l0 = min(max((int)v0, 0), 3);
  l1 = min(max((int)v1, 0), 3);
  l2 = min(max((int)v2, 0), 3);
  f0 = v0 - (float)l0; f1 = v1 - (float)l1; f2 = v2 - (float)l2;
}

// K1: per-cell histogram + in-degree (R4-proven) + grid-stride agg zeroing
// (agg is write-only here and not consumed until k_edge, 2 dispatches later).
__global__ void k_hist(const float* __restrict__ attr, const int* __restrict__ edst,
                       int* __restrict__ hist, int* __restrict__ degi,
                       float* __restrict__ agg) {
  __shared__ int lh[64];
  if (threadIdx.x < 64) lh[threadIdx.x] = 0;
  __syncthreads();
  int gid = blockIdx.x * blockDim.x + threadIdx.x;
  int gsz = gridDim.x * blockDim.x;
  for (int i = gid; i < NN * COUT; i += gsz) agg[i] = 0.0f;
  for (int e = gid; e < EE; e += gsz) {
    int l0, l1, l2; float f0, f1, f2;
    cell_of(attr[e*3], attr[e*3+1], attr[e*3+2], l0, l1, l2, f0, f1, f2);
    atomicAdd(&lh[l0 | (l1 << 2) | (l2 << 4)], 1);
    atomicAdd(&degi[edst[e]], 1);
  }
  __syncthreads();
  if (threadIdx.x < 64 && lh[threadIdx.x]) atomicAdd(&hist[threadIdx.x], lh[threadIdx.x]);
}

// K2: two-level scatter into cell buckets (R4-proven) with the 64-bin global
// prefix computed in-block (thread 0, 64 adds) -- k_prefix dispatch removed.
__global__ void k_scatter(const float* __restrict__ attr, const int* __restrict__ hist,
                          int* __restrict__ cursors, int* __restrict__ sorted) {
  __shared__ int lcnt[64], lbase[64], lcur[64], goff[64];
  int tid = threadIdx.x;
  if (tid < 64) { lcnt[tid] = 0; lcur[tid] = 0; }
  __syncthreads();
  int per = (EE + gridDim.x - 1) / gridDim.x;
  int b0 = blockIdx.x * per;
  int b1 = min(b0 + per, EE);
  for (int e = b0 + tid; e < b1; e += blockDim.x) {
    int l0, l1, l2; float f0, f1, f2;
    cell_of(attr[e*3], attr[e*3+1], attr[e*3+2], l0, l1, l2, f0, f1, f2);
    atomicAdd(&lcnt[l0 | (l1 << 2) | (l2 << 4)], 1);
  }
  __syncthreads();
  if (tid == 0) { int r = 0; for (int c = 0; c < 64; ++c) { goff[c] = r; r += hist[c]; } }
  __syncthreads();
  if (tid < 64 && lcnt[tid]) lbase[tid] = goff[tid] + atomicAdd(&cursors[tid], lcnt[tid]);
  __syncthreads();
  for (int e = b0 + tid; e < b1; e += blockDim.x) {
    int l0, l1, l2; float f0, f1, f2;
    cell_of(attr[e*3], attr[e*3+1], attr[e*3+2], l0, l1, l2, f0, f1, f2);
    int c = l0 | (l1 << 2) | (l2 << 4);
    int p = atomicAdd(&lcur[c], 1);
    sorted[lbase[c] + p] = e;
  }
}

// K3: MFMA edge kernel -- bit-for-bit the R4 kernel measured at 54 us.
// One wave per 32-edge tile of the cell-sorted list; two masked passes at
// cell boundaries; D layout col=lane&31, row=(r&3)+8*(r>>2)+4*half; f32
// atomics, 2x128B dense per instruction.
__global__ __launch_bounds__(256) void k_edge(
    const float* __restrict__ x, const int* __restrict__ esrc, const int* __restrict__ edst,
    const float* __restrict__ attr, const float* __restrict__ weight,
    const int* __restrict__ sorted, float* __restrict__ agg) {
  int gwave = (int)((blockIdx.x * blockDim.x + threadIdx.x) >> 6);
  if (gwave >= NTILES) return;
  int lane = threadIdx.x & 63;
  int col = lane & 31;
  int half = lane >> 5;

  int p = gwave * 32 + col;
  int e = sorted[p];
  float a0 = attr[e*3+0], a1 = attr[e*3+1], a2 = attr[e*3+2];
  int src = esrc[e];
  int dst = edst[e];

  float v0 = a0 * 4.0f, v1 = a1 * 4.0f, v2 = a2 * 4.0f;
  int l0 = min(max((int)v0, 0), 3);
  int l1 = min(max((int)v1, 0), 3);
  int l2 = min(max((int)v2, 0), 3);
  float f0 = v0 - (float)l0, f1 = v1 - (float)l1, f2 = v2 - (float)l2;
  int mycell = l0 | (l1 << 2) | (l2 << 4);

  const float* xp = x + src * CIN + half * 8;
  float xs[8];
  {
    f32x4 xa = *(const f32x4*)xp;
    f32x4 xb = *(const f32x4*)(xp + 4);
#pragma unroll
    for (int j = 0; j < 4; ++j) { xs[j] = xa[j]; xs[j + 4] = xb[j]; }
  }

  int c_first = __builtin_amdgcn_readfirstlane(mycell);
  int c_last  = __builtin_amdgcn_readfirstlane(__shfl(mycell, 31, 64));
  int npass = (c_first == c_last) ? 1 : 2;

  f32x16 acc;
#pragma unroll
  for (int r = 0; r < 16; ++r) acc[r] = 0.0f;

  float g0 = 1.0f - f0, g1 = 1.0f - f1, g2 = 1.0f - f2;

  for (int pass = 0; pass < npass; ++pass) {
    int cell = pass ? c_last : c_first;
    int c0 = cell & 3, c1 = (cell >> 2) & 3, c2 = cell >> 4;
    bool act = (mycell == cell);
#pragma unroll
    for (int cb = 0; cb < 8; ++cb) {
      float w = ((cb & 1) ? f0 : g0) * (((cb >> 1) & 1) ? f1 : g1) * (((cb >> 2) & 1) ? f2 : g2);
      w = act ? w : 0.0f;
      short8 av;
#pragma unroll
      for (int j = 0; j < 8; ++j)
        av[j] = __builtin_bit_cast(short, (__bf16)(w * xs[j]));
      int wi = (c0 + (cb & 1)) + 5 * (c1 + ((cb >> 1) & 1)) + 25 * (c2 + (cb >> 2));
      const float* wp = weight + wi * (CIN * COUT) + (half * 8) * COUT + col;
      short8 bv;
#pragma unroll
      for (int j = 0; j < 8; ++j)
        bv[j] = __builtin_bit_cast(short, (__bf16)wp[j * COUT]);
      acc = __builtin_amdgcn_mfma_f32_32x32x16_bf16(av, bv, acc, 0, 0, 0);
    }
  }

#pragma unroll
  for (int r = 0; r < 16; ++r) {
    int orow = (r & 3) + 8 * (r >> 2) + 4 * half;
    int d = __shfl(dst, orow, 64);
    atomicAdd(&agg[d * COUT + col], acc[r]);
  }
}

// K4: node kernel, grid-stride 256 blocks (R7-proven form, f32 agg):
// mean, x@root+bias, ELU, write h, BN partials in registers -> 16k gsum RMWs.
__global__ __launch_bounds__(1024) void k_node(
    const float* __restrict__ x, const float* __restrict__ agg,
    const int* __restrict__ degi,
    const float* __restrict__ root, const float* __restrict__ bias,
    float* __restrict__ hout, float* __restrict__ gsum, float* __restrict__ gsumsq) {
  int tid = threadIdx.x;
  int o = tid & 31;
  int nl = tid >> 5;                 // node-in-tile, 0..31
  float s1 = 0.0f, s2 = 0.0f;
  const int NTILE = (NN + 31) / 32;  // 1563
  for (int t = blockIdx.x; t < NTILE; t += gridDim.x) {
    int n = t * 32 + nl;
    if (n < NN) {
      float a = agg[n * COUT + o] / fmaxf((float)degi[n], 1.0f);
      const float* xp = x + n * CIN;
      float r = 0.0f;
#pragma unroll
      for (int i = 0; i < CIN; ++i) r = fmaf(xp[i], root[i * COUT + o], r);
      float hv = a + r + bias[o];
      hv = hv > 0.0f ? hv : expm1f(hv);
      hout[n * COUT + o] = hv;
      s1 += hv; s2 += hv * hv;
    }
  }
  s1 += __shfl_xor(s1, 32);
  s2 += __shfl_xor(s2, 32);
  __shared__ float sred[2][16][32];
  int w = tid >> 6;
  if ((tid & 63) < 32) { sred[0][w][o] = s1; sred[1][w][o] = s2; }
  __syncthreads();
  if (tid < 32) {
    float t1 = 0.0f, t2 = 0.0f;
#pragma unroll
    for (int w2 = 0; w2 < 16; ++w2) { t1 += sred[0][w2][o]; t2 += sred[1][w2][o]; }
    atomicAdd(&gsum[o], t1);
    atomicAdd(&gsumsq[o], t2);
  }
}

// K5: finalize BatchNorm in-place
__global__ void k_bn(float* __restrict__ out, const float* __restrict__ gsum,
                     const float* __restrict__ gsumsq, const float* __restrict__ gamma,
                     const float* __restrict__ beta) {
  int idx = blockIdx.x * blockDim.x + threadIdx.x;
  if (idx >= NN * COUT) return;
  int o = idx & 31;
  float m = gsum[o] * (1.0f / NN);
  float var = gsumsq[o] * (1.0f / NN) - m * m;
  float inv = rsqrtf(var + 1e-5f);
  out[idx] = (out[idx] - m) * inv * gamma[o] + beta[o];
}

extern "C" void kernel_launch(void* const* d_in, const int* in_sizes, int n_in,
                              void* d_out, int out_size, void* d_ws, size_t ws_size,
                              hipStream_t stream) {
  const float* x      = (const float*)d_in[0];
  const int*   ei     = (const int*)d_in[1];
  const float* attr   = (const float*)d_in[2];
  const float* weight = (const float*)d_in[3];
  const float* root   = (const float*)d_in[4];
  const float* bias   = (const float*)d_in[5];
  const float* gamma  = (const float*)d_in[6];
  const float* beta   = (const float*)d_in[7];
  float* out = (float*)d_out;
  char* ws = (char*)d_ws;
  const int* esrc = ei;
  const int* edst = ei + EE;

  float* agg     = (float*)(ws + W_AGG);
  int*   degi    = (int*)(ws + W_DEG);
  int*   hist    = (int*)(ws + W_HIST);
  int*   cursors = (int*)(ws + W_CUR);
  float* gsum    = (float*)(ws + W_SUM);
  float* gsumsq  = (float*)(ws + W_SUMSQ);
  int*   sorted  = (int*)(ws + W_SORT);

  hipMemsetAsync(ws + W_DEG, 0, W_ZEND - W_DEG, stream);   // 201 KB only
  k_hist<<<512, 256, 0, stream>>>(attr, edst, hist, degi, agg);
  k_scatter<<<512, 256, 0, stream>>>(attr, hist, cursors, sorted);
  k_edge<<<NTILES / 4, 256, 0, stream>>>(x, esrc, edst, attr, weight, sorted, agg);
  k_node<<<256, 1024, 0, stream>>>(x, agg, degi, root, bias, out, gsum, gsumsq);
  k_bn<<<(NN * COUT) / 256, 256, 0, stream>>>(out, gsum, gsumsq, gamma, beta);
}